// Round 13
// baseline (423.392 us; speedup 1.0000x reference)
//
#include <hip/hip_runtime.h>
#include <cstdint>
#include <cstddef>

#define N_DIM 128
#define QKV_DIM 384
#define NUM_HEADS 8
#define HEAD_DIM 16
#define SCAN_B 256
#define SCAN_V 4
#define SCAN_TILE (SCAN_B * SCAN_V)   // 1024 elements per scan block

typedef unsigned int uint;
typedef unsigned short ushort;
typedef __attribute__((ext_vector_type(8))) short short8;   // 8 bf16 = 4 VGPRs
typedef __attribute__((ext_vector_type(4))) float f32x4;    // MFMA accumulator

__device__ __forceinline__ ushort f2bf(float f) {
    uint u = __float_as_uint(f);
    uint r = u + 0x7fffu + ((u >> 16) & 1u);   // round-to-nearest-even
    return (ushort)(r >> 16);
}
__device__ __forceinline__ float bf_lo(uint u) { return __uint_as_float(u << 16); }
__device__ __forceinline__ float bf_hi(uint u) { return __uint_as_float(u & 0xffff0000u); }

// 16-term bf16 k-row dot q (k row pointer, q staged [d][h]).
__device__ __forceinline__ float kdot(const uint* kr, const float (*qsc)[8], int h2) {
    uint4 A = *((const uint4*)kr);
    uint4 B = *((const uint4*)(kr + 4));
    float dot = 0.f;
    dot = fmaf(bf_lo(A.x), qsc[0][h2],  dot); dot = fmaf(bf_hi(A.x), qsc[1][h2],  dot);
    dot = fmaf(bf_lo(A.y), qsc[2][h2],  dot); dot = fmaf(bf_hi(A.y), qsc[3][h2],  dot);
    dot = fmaf(bf_lo(A.z), qsc[4][h2],  dot); dot = fmaf(bf_hi(A.z), qsc[5][h2],  dot);
    dot = fmaf(bf_lo(A.w), qsc[6][h2],  dot); dot = fmaf(bf_hi(A.w), qsc[7][h2],  dot);
    dot = fmaf(bf_lo(B.x), qsc[8][h2],  dot); dot = fmaf(bf_hi(B.x), qsc[9][h2],  dot);
    dot = fmaf(bf_lo(B.y), qsc[10][h2], dot); dot = fmaf(bf_hi(B.y), qsc[11][h2], dot);
    dot = fmaf(bf_lo(B.z), qsc[12][h2], dot); dot = fmaf(bf_hi(B.z), qsc[13][h2], dot);
    dot = fmaf(bf_lo(B.w), qsc[14][h2], dot); dot = fmaf(bf_hi(B.w), qsc[15][h2], dot);
    return dot;
}

// ---------------------------------------------------------------------------
// Pack W (fp32, 128 x N) into B-fragment-major bf16 (both Wqkv and Wout in
// one launch):
// Wp[((T*4+s)*64 + lane)*8 + j] = bf16(W[s*32 + (lane>>4)*8 + j][T*16 + (lane&15)])
// ---------------------------------------------------------------------------
__global__ void pack_w_kernel(const float* __restrict__ Wq, const float* __restrict__ Wo,
                              ushort* __restrict__ WpQ, ushort* __restrict__ WpO) {
    int idx = blockIdx.x * blockDim.x + threadIdx.x;
    const float* W;
    ushort* Wp;
    int N;
    if (idx < 128 * QKV_DIM) {
        W = Wq; Wp = WpQ; N = QKV_DIM;
    } else {
        idx -= 128 * QKV_DIM;
        if (idx >= 128 * N_DIM) return;
        W = Wo; Wp = WpO; N = N_DIM;
    }
    int j = idx & 7;
    int l = (idx >> 3) & 63;
    int fs = idx >> 9;                // T*4 + s
    int T = fs >> 2, s = fs & 3;
    int k = s * 32 + (l >> 4) * 8 + j;
    int c = T * 16 + (l & 15);
    Wp[idx] = f2bf(W[k * N + c]);
}

// ---------------------------------------------------------------------------
// QKV GEMM via MFMA + fused dst-histogram.
// (n x 128 fp32 x, converted in-register) @ (128 x 384). 4 waves/block,
// 16 nodes/wave. Outputs staged in LDS per wave, flushed at half-row
// granularity with coalesced 16B/lane stores. Histogram of dst folded in
// as a grid-stride prologue. k/v in SEPARATE 256B-row tables (r11 win).
// ---------------------------------------------------------------------------
__global__ __launch_bounds__(256) void qkv_gemm(const float* __restrict__ x,
                                                const ushort* __restrict__ Wp,
                                                const float* __restrict__ bqkv,
                                                float* __restrict__ qtab,
                                                ushort* __restrict__ ktab,
                                                ushort* __restrict__ vtab,
                                                const int* __restrict__ dst,
                                                int* __restrict__ counts,
                                                int n, int nE) {
    // fused histogram (no dependency on GEMM data)
    {
        int stride = gridDim.x * blockDim.x;
        for (int e = blockIdx.x * blockDim.x + threadIdx.x; e < nE; e += stride)
            atomicAdd(&counts[dst[e]], 1);
    }
    __shared__ float  lq[4][16][64];     // [wave][node][q col_local] 4KB/wave
    __shared__ ushort lk[4][16][64];     // [wave][node][k elem_local] 2KB/wave
    __shared__ ushort lv[4][16][64];     // [wave][node][v elem_local] 2KB/wave
    int w = threadIdx.x >> 6, lane = threadIdx.x & 63;
    int node0 = blockIdx.x * 64 + w * 16;
    int m = lane & 15, quad = lane >> 4;
    int arow = node0 + m; if (arow >= n) arow = n - 1;
    const float* xr = x + (size_t)arow * N_DIM;
    short8 A[4];
    #pragma unroll
    for (int s = 0; s < 4; ++s) {
        float4 f0 = *(const float4*)(xr + s * 32 + quad * 8);
        float4 f1 = *(const float4*)(xr + s * 32 + quad * 8 + 4);
        uint u0 = (uint)f2bf(f0.x) | ((uint)f2bf(f0.y) << 16);
        uint u1 = (uint)f2bf(f0.z) | ((uint)f2bf(f0.w) << 16);
        uint u2 = (uint)f2bf(f1.x) | ((uint)f2bf(f1.y) << 16);
        uint u3 = (uint)f2bf(f1.z) | ((uint)f2bf(f1.w) << 16);
        uint4 u = make_uint4(u0, u1, u2, u3);
        A[s] = *(short8*)&u;
    }
    for (int half = 0; half < 2; ++half) {
        for (int T12 = 0; T12 < 12; ++T12) {
            int T = half * 12 + T12;
            f32x4 acc = {0.f, 0.f, 0.f, 0.f};
            const ushort* bp = Wp + ((size_t)(T * 4) * 64 + lane) * 8;
            #pragma unroll
            for (int s = 0; s < 4; ++s) {
                uint4 u = *(const uint4*)(bp + s * 512);
                short8 B = *(short8*)&u;
                acc = __builtin_amdgcn_mfma_f32_16x16x32_bf16(A[s], B, acc, 0, 0, 0);
            }
            int c = T * 16 + m;               // original qkv column (for bias)
            int hq = T / 3, wvv = T % 3;      // head, {0=q,1=k,2=v}
            int hl = hq - half * 4;           // head local to this half (0..3)
            float bb = bqkv[c];
            #pragma unroll
            for (int r = 0; r < 4; ++r) {
                int nd16 = quad * 4 + r;
                float v = acc[r] + bb;
                if (wvv == 0)      lq[w][nd16][hl * 16 + m] = v;
                else if (wvv == 1) lk[w][nd16][hl * 16 + m] = f2bf(v);
                else               lv[w][nd16][hl * 16 + m] = f2bf(v);
            }
        }
        // flush this half: q cols [half*64,+64), k/v elems [half*64,+64) per
        // node; 16B/lane coalesced stores.
        #pragma unroll
        for (int rr = 0; rr < 4; ++rr) {
            int of = rr * 256 + lane * 4;          // float idx into lq[w]
            int ndq = of >> 6, colq = of & 63;
            float4 qv = *(const float4*)&lq[w][ndq][colq];
            int gq = node0 + ndq;
            if (gq < n)
                *(float4*)(qtab + (size_t)gq * N_DIM + half * 64 + colq) = qv;
        }
        #pragma unroll
        for (int rr = 0; rr < 2; ++rr) {
            int ou = rr * 512 + lane * 8;          // ushort idx (1024 total)
            int ndk = ou >> 6, elk = ou & 63;
            int gk = node0 + ndk;
            uint4 kv4 = *(const uint4*)&lk[w][ndk][elk];
            uint4 vv4 = *(const uint4*)&lv[w][ndk][elk];
            if (gk < n) {
                *(uint4*)(ktab + (size_t)gk * 128 + half * 64 + elk) = kv4;
                *(uint4*)(vtab + (size_t)gk * 128 + half * 64 + elk) = vv4;
            }
        }
    }
}

// ---------------------------------------------------------------------------
// Output GEMM via MFMA: (n x 128 bf16 agg) @ (128 x 128) + bout -> fp32 out.
// ---------------------------------------------------------------------------
__global__ __launch_bounds__(256) void out_gemm(const uint* __restrict__ aggb,
                                                const ushort* __restrict__ Wp,
                                                const float* __restrict__ bout,
                                                float* __restrict__ out, int n) {
    int w = threadIdx.x >> 6, lane = threadIdx.x & 63;
    int node0 = blockIdx.x * 64 + w * 16;
    int m = lane & 15, quad = lane >> 4;
    int arow = node0 + m; if (arow >= n) arow = n - 1;
    const uint* ar = aggb + (size_t)arow * 64;
    short8 A[4];
    #pragma unroll
    for (int s = 0; s < 4; ++s) {
        uint4 u = *(const uint4*)(ar + s * 16 + quad * 4);
        A[s] = *(short8*)&u;
    }
    for (int T = 0; T < 8; ++T) {
        f32x4 acc = {0.f, 0.f, 0.f, 0.f};
        const ushort* bp = Wp + ((size_t)(T * 4) * 64 + lane) * 8;
        #pragma unroll
        for (int s = 0; s < 4; ++s) {
            uint4 u = *(const uint4*)(bp + s * 512);
            short8 B = *(short8*)&u;
            acc = __builtin_amdgcn_mfma_f32_16x16x32_bf16(A[s], B, acc, 0, 0, 0);
        }
        int c = T * 16 + m;
        float bb = bout[c];
        #pragma unroll
        for (int r = 0; r < 4; ++r) {
            int nd = node0 + quad * 4 + r;
            if (nd < n) out[(size_t)nd * N_DIM + c] = acc[r] + bb;
        }
    }
}

// ---------------------------------------------------------------------------
// CSR build: exclusive scan of counts, sharded scatter of src ids.
// (histogram is fused into qkv_gemm.)
// ---------------------------------------------------------------------------
__global__ void scan1_kernel(const int* __restrict__ counts, int* __restrict__ offs,
                             int* __restrict__ partials, int n) {
    __shared__ int ts[SCAN_B];
    int t = threadIdx.x;
    int base = blockIdx.x * SCAN_TILE + t * SCAN_V;
    int v[SCAN_V];
    int s = 0;
    #pragma unroll
    for (int i = 0; i < SCAN_V; ++i) { v[i] = (base + i < n) ? counts[base + i] : 0; s += v[i]; }
    ts[t] = s;
    __syncthreads();
    for (int off = 1; off < SCAN_B; off <<= 1) {
        int x = (t >= off) ? ts[t - off] : 0;
        __syncthreads();
        ts[t] += x;
        __syncthreads();
    }
    int run = (t > 0) ? ts[t - 1] : 0;
    if (t == SCAN_B - 1) partials[blockIdx.x] = ts[SCAN_B - 1];
    #pragma unroll
    for (int i = 0; i < SCAN_V; ++i) { if (base + i < n) offs[base + i] = run; run += v[i]; }
}

__global__ void scan2_kernel(int* __restrict__ partials, int P) {
    __shared__ int ps[1024];
    int t = threadIdx.x;
    ps[t] = (t < P) ? partials[t] : 0;
    __syncthreads();
    for (int off = 1; off < 1024; off <<= 1) {
        int x = (t >= off) ? ps[t - off] : 0;
        __syncthreads();
        ps[t] += x;
        __syncthreads();
    }
    if (t < P) partials[t] = (t > 0) ? ps[t - 1] : 0;
}

__global__ void scan3_kernel(int* __restrict__ offs, const int* __restrict__ partials,
                             int* __restrict__ cursor, int n, int nE) {
    int i = blockIdx.x * blockDim.x + threadIdx.x;
    if (i < n) {
        int o = offs[i] + partials[i / SCAN_TILE];
        offs[i] = o;
        cursor[i] = o;
    }
    if (i == 0) offs[n] = nE;
}

// Sharded scatter, v12: 4 shards (was 8). Each block reads all dst once per
// shard -> dst read traffic halves (51MB -> 25.6MB). A shard's esrc region
// (~1.6MB) still fits an XCD L2; its blocks now land on 2 XCDs (bid&3 under
// round-robin dispatch) — bounded cross-XCD cursor traffic, revert if total
// regresses. Correctness does not depend on the XCD mapping.
__global__ __launch_bounds__(256) void scatter_src_shard(const int* __restrict__ src,
                                                         const int* __restrict__ dst,
                                                         int* __restrict__ cursor,
                                                         int* __restrict__ esrc,
                                                         int nE, int shardSize) {
    int shard = blockIdx.x & 3;
    int sub   = blockIdx.x >> 2;
    int nsub  = gridDim.x >> 2;
    int lo = shard * shardSize;
    int hi = lo + shardSize;
    int stride = nsub * blockDim.x;
    for (int e = sub * blockDim.x + threadIdx.x; e < nE; e += stride) {
        int d = dst[e];
        if (d >= lo && d < hi) {
            int pos = atomicAdd(&cursor[d], 1);
            esrc[pos] = src[e];
        }
    }
}

// ---------------------------------------------------------------------------
// Fused attention v12 = v11 (117.4us: block-per-node, 128 threads, split
// 256B k/v rows, byte-offset so[], 3 lockstep barriers, ALWAYS-padded
// batches, phase-A denom + end reduce) + ADAPTIVE 32-EDGE CHUNKS:
//  deg ~ Poisson(16): ~43% of nodes have deg>16 and previously ran TWO full
//  3-barrier chunk rounds. When rem>16 we now process 32 edges in ONE round:
//  phase A scores 2 edges/thread (2 k-rows in flight), phase B runs a
//  32-deep load batch (2x loads in flight). Total loads unchanged (same 32
//  slots), barrier-phases halve for those nodes. rem<=16 takes the identical
//  v11 path. Block-uniform branch.
// ---------------------------------------------------------------------------
__global__ void attn_kernel(const float* __restrict__ qtab,
                            const uint* __restrict__ kt, const uint* __restrict__ vt,
                            const int* __restrict__ esrc, const int* __restrict__ offs,
                            ushort* __restrict__ aggb, int n) {
    int node = blockIdx.x;
    int t = threadIdx.x;              // 0..127
    __shared__ float qs[16][8];       // q transposed: [d][h] (conflict-free)
    __shared__ uint  so[32];          // chunk src row BYTE offsets (0-padded)
    __shared__ float pp[32][8];       // chunk exp(score) (0-padded)
    __shared__ float lw[2][8];        // per-wave denom partials
    int h  = t >> 4, dd = t & 15;     // accumulate mapping
    int h2 = t & 7,  el = t >> 3;     // score mapping (0..15 across block)
    {
        float qv = qtab[(size_t)node * N_DIM + t];   // coalesced
        qs[dd][h] = qv;
    }
    int start = offs[node];
    int deg = offs[node + 1] - start;
    float lsum = 0.f, acc = 0.f;
    uint voffb = (uint)h * 32u + (uint)(dd >> 1) * 4u;   // v word byte off (256B row)
    uint sh = (dd & 1) ? 0u : 16u;    // branchless bf16 extract shift
    __syncthreads();

    for (int c0 = 0; c0 < deg; c0 += 32) {
        int rem = deg - c0;
        if (rem > 16) {
            // ---- 32-edge merged round ----
            int cn = rem < 32 ? rem : 32;
            if (t < 32) so[t] = (t < cn) ? ((uint)esrc[start + c0 + t] << 8) : 0u;
            __syncthreads();
            // phase A: edges el (el<16<=cn: unguarded) and el+16 (guarded;
            // padded slot loads row 0, L1-hot, pv forced to 0).
            const uint* kr0 = (const uint*)((const char*)kt + (so[el] + (uint)(h2 * 32)));
            const uint* kr1 = (const uint*)((const char*)kt + (so[el + 16] + (uint)(h2 * 32)));
            float d0 = kdot(kr0, qs, h2);
            float d1 = kdot(kr1, qs, h2);
            float pv0 = __expf(d0 * 0.25f);                             // 1/sqrt(16)
            float pv1 = (el + 16 < cn) ? __expf(d1 * 0.25f) : 0.f;
            pp[el][h2] = pv0;
            pp[el + 16][h2] = pv1;
            lsum += pv0 + pv1;
            __syncthreads();
            // phase B: 32 loads in flight (padded: row 0, p=0).
            float vacc = 0.f;
            uint vv[32];
            #pragma unroll
            for (int i = 0; i < 32; ++i)
                vv[i] = *(const uint*)((const char*)vt + (so[i] + voffb));
            #pragma unroll
            for (int i = 0; i < 32; ++i) {
                float p = pp[i][h];
                float v = __uint_as_float((vv[i] << sh) & 0xffff0000u);
                vacc = fmaf(p, v, vacc);
            }
            acc += vacc;
            __syncthreads();
        } else {
            // ---- 16-edge round (identical to v11) ----
            int cn = rem;             // 1..16
            if (t < 16) so[t] = (t < cn) ? ((uint)esrc[start + c0 + t] << 8) : 0u;
            __syncthreads();
            float pv = 0.f;
            if (el < cn) {
                const uint* kr = (const uint*)((const char*)kt + (so[el] + (uint)(h2 * 32)));
                pv = __expf(kdot(kr, qs, h2) * 0.25f);
            }
            pp[el][h2] = pv;
            lsum += pv;
            __syncthreads();
            float vacc = 0.f;
            uint vv[16];
            #pragma unroll
            for (int i = 0; i < 16; ++i)
                vv[i] = *(const uint*)((const char*)vt + (so[i] + voffb));
            #pragma unroll
            for (int i = 0; i < 16; ++i) {
                float p = pp[i][h];
                float v = __uint_as_float((vv[i] << sh) & 0xffff0000u);
                vacc = fmaf(p, v, vacc);
            }
            acc += vacc;
            __syncthreads();
        }
    }
    // reduce lsum over el: el = bits 3..5 of the in-wave lane id (+ wave id).
    lsum += __shfl_xor(lsum, 8, 64);
    lsum += __shfl_xor(lsum, 16, 64);
    lsum += __shfl_xor(lsum, 32, 64);
    if ((t & 63) < 8) lw[t >> 6][t & 7] = lsum;   // per-wave partial per head
    __syncthreads();
    float L = lw[0][h] + lw[1][h];
    float rL = (L > 0.f) ? __frcp_rn(L) : 0.f;
    aggb[(size_t)node * N_DIM + t] = f2bf(acc * rL);
}

extern "C" void kernel_launch(void* const* d_in, const int* in_sizes, int n_in,
                              void* d_out, int out_size, void* d_ws, size_t ws_size,
                              hipStream_t stream) {
    const float* x    = (const float*)d_in[0];
    const float* Wqkv = (const float*)d_in[1];
    const float* bqkv = (const float*)d_in[2];
    const float* Wout = (const float*)d_in[3];
    const float* bout = (const float*)d_in[4];
    const int*   src  = (const int*)d_in[5];
    const int*   dst  = (const int*)d_in[6];
    float* out = (float*)d_out;

    const int n  = in_sizes[0] / N_DIM;   // 100000
    const int nE = in_sizes[5];           // 1600000

    // Workspace layout (4-byte units):
    uint* ws = (uint*)d_ws;
    float*  qtab   = (float*)ws;                          // n * 128 fp32
    uint*   ktab   = ws + (size_t)n * 128;                // n * 64 uint (128 bf16)
    uint*   vtab   = ktab + (size_t)n * 64;               // n * 64 uint (128 bf16)
    uint*   aggb   = vtab + (size_t)n * 64;               // n * 64 uint (128 bf16)
    ushort* WpQ    = (ushort*)(aggb + (size_t)n * 64);    // 128*384 bf16
    ushort* WpO    = WpQ + 128 * QKV_DIM;                 // 128*128 bf16
    int*    counts = (int*)(WpO + 128 * N_DIM);           // n
    int*    offs   = counts + n;                          // n + 1
    int*    cursor = offs + n + 1;                        // n
    int*    partials = cursor + n;                        // up to 1024
    int*    esrc   = partials + 1024;                     // nE

    hipMemsetAsync(counts, 0, (size_t)n * sizeof(int), stream);

    pack_w_kernel<<<(128 * (QKV_DIM + N_DIM) + 255) / 256, 256, 0, stream>>>(Wqkv, Wout, WpQ, WpO);

    qkv_gemm<<<(n + 63) / 64, 256, 0, stream>>>(x, WpQ, bqkv, qtab,
                                                (ushort*)ktab, (ushort*)vtab,
                                                dst, counts, n, nE);

    int P = (n + SCAN_TILE - 1) / SCAN_TILE;              // 98
    scan1_kernel<<<P, SCAN_B, 0, stream>>>(counts, offs, partials, n);
    scan2_kernel<<<1, 1024, 0, stream>>>(partials, P);
    scan3_kernel<<<(n + 255) / 256, 256, 0, stream>>>(offs, partials, cursor, n, nE);

    int shardSize = (n + 3) / 4;                          // 25000
    scatter_src_shard<<<4 * 256, 256, 0, stream>>>(src, dst, cursor, esrc, nE, shardSize);

    attn_kernel<<<n, 128, 0, stream>>>(qtab, ktab, vtab, esrc, offs, (ushort*)aggb, n);

    out_gemm<<<(n + 63) / 64, 256, 0, stream>>>(aggb, WpO, bout, out, n);
}

// Round 14
// 414.269 us; speedup vs baseline: 1.0220x; 1.0220x over previous
//
#include <hip/hip_runtime.h>
#include <cstdint>
#include <cstddef>

#define N_DIM 128
#define QKV_DIM 384
#define NUM_HEADS 8
#define HEAD_DIM 16
#define SCAN_B 256
#define SCAN_V 4
#define SCAN_TILE (SCAN_B * SCAN_V)   // 1024 elements per scan block

typedef unsigned int uint;
typedef unsigned short ushort;
typedef __attribute__((ext_vector_type(8))) short short8;   // 8 bf16 = 4 VGPRs
typedef __attribute__((ext_vector_type(4))) float f32x4;    // MFMA accumulator

__device__ __forceinline__ ushort f2bf(float f) {
    uint u = __float_as_uint(f);
    uint r = u + 0x7fffu + ((u >> 16) & 1u);   // round-to-nearest-even
    return (ushort)(r >> 16);
}
__device__ __forceinline__ float bf_lo(uint u) { return __uint_as_float(u << 16); }
__device__ __forceinline__ float bf_hi(uint u) { return __uint_as_float(u & 0xffff0000u); }

// 16-term bf16 k-row dot q (k row pointer, q staged [d][h]).
__device__ __forceinline__ float kdot(const uint* kr, const float (*qsc)[8], int h2) {
    uint4 A = *((const uint4*)kr);
    uint4 B = *((const uint4*)(kr + 4));
    float dot = 0.f;
    dot = fmaf(bf_lo(A.x), qsc[0][h2],  dot); dot = fmaf(bf_hi(A.x), qsc[1][h2],  dot);
    dot = fmaf(bf_lo(A.y), qsc[2][h2],  dot); dot = fmaf(bf_hi(A.y), qsc[3][h2],  dot);
    dot = fmaf(bf_lo(A.z), qsc[4][h2],  dot); dot = fmaf(bf_hi(A.z), qsc[5][h2],  dot);
    dot = fmaf(bf_lo(A.w), qsc[6][h2],  dot); dot = fmaf(bf_hi(A.w), qsc[7][h2],  dot);
    dot = fmaf(bf_lo(B.x), qsc[8][h2],  dot); dot = fmaf(bf_hi(B.x), qsc[9][h2],  dot);
    dot = fmaf(bf_lo(B.y), qsc[10][h2], dot); dot = fmaf(bf_hi(B.y), qsc[11][h2], dot);
    dot = fmaf(bf_lo(B.z), qsc[12][h2], dot); dot = fmaf(bf_hi(B.z), qsc[13][h2], dot);
    dot = fmaf(bf_lo(B.w), qsc[14][h2], dot); dot = fmaf(bf_hi(B.w), qsc[15][h2], dot);
    return dot;
}

// ---------------------------------------------------------------------------
// Pack W (fp32, 128 x N) into B-fragment-major bf16 (both Wqkv and Wout in
// one launch) + zero the counts histogram (idle index range; removes the
// separate hipMemsetAsync launch from the serial graph):
// Wp[((T*4+s)*64 + lane)*8 + j] = bf16(W[s*32 + (lane>>4)*8 + j][T*16 + (lane&15)])
// ---------------------------------------------------------------------------
__global__ void pack_w_kernel(const float* __restrict__ Wq, const float* __restrict__ Wo,
                              ushort* __restrict__ WpQ, ushort* __restrict__ WpO,
                              int* __restrict__ counts, int n) {
    int idx = blockIdx.x * blockDim.x + threadIdx.x;
    if (idx < n) counts[idx] = 0;
    const float* W;
    ushort* Wp;
    int N;
    if (idx < 128 * QKV_DIM) {
        W = Wq; Wp = WpQ; N = QKV_DIM;
    } else {
        idx -= 128 * QKV_DIM;
        if (idx >= 128 * N_DIM) return;
        W = Wo; Wp = WpO; N = N_DIM;
    }
    int j = idx & 7;
    int l = (idx >> 3) & 63;
    int fs = idx >> 9;                // T*4 + s
    int T = fs >> 2, s = fs & 3;
    int k = s * 32 + (l >> 4) * 8 + j;
    int c = T * 16 + (l & 15);
    Wp[idx] = f2bf(W[k * N + c]);
}

// ---------------------------------------------------------------------------
// QKV GEMM via MFMA + fused dst-histogram.
// (n x 128 fp32 x, converted in-register) @ (128 x 384). 4 waves/block,
// 16 nodes/wave. Outputs staged in LDS per wave, flushed at half-row
// granularity with coalesced 16B/lane stores. Histogram of dst folded in
// as a grid-stride prologue. k/v in SEPARATE 256B-row tables (r11 win).
// ---------------------------------------------------------------------------
__global__ __launch_bounds__(256) void qkv_gemm(const float* __restrict__ x,
                                                const ushort* __restrict__ Wp,
                                                const float* __restrict__ bqkv,
                                                float* __restrict__ qtab,
                                                ushort* __restrict__ ktab,
                                                ushort* __restrict__ vtab,
                                                const int* __restrict__ dst,
                                                int* __restrict__ counts,
                                                int n, int nE) {
    // fused histogram (no dependency on GEMM data)
    {
        int stride = gridDim.x * blockDim.x;
        for (int e = blockIdx.x * blockDim.x + threadIdx.x; e < nE; e += stride)
            atomicAdd(&counts[dst[e]], 1);
    }
    __shared__ float  lq[4][16][64];     // [wave][node][q col_local] 4KB/wave
    __shared__ ushort lk[4][16][64];     // [wave][node][k elem_local] 2KB/wave
    __shared__ ushort lv[4][16][64];     // [wave][node][v elem_local] 2KB/wave
    int w = threadIdx.x >> 6, lane = threadIdx.x & 63;
    int node0 = blockIdx.x * 64 + w * 16;
    int m = lane & 15, quad = lane >> 4;
    int arow = node0 + m; if (arow >= n) arow = n - 1;
    const float* xr = x + (size_t)arow * N_DIM;
    short8 A[4];
    #pragma unroll
    for (int s = 0; s < 4; ++s) {
        float4 f0 = *(const float4*)(xr + s * 32 + quad * 8);
        float4 f1 = *(const float4*)(xr + s * 32 + quad * 8 + 4);
        uint u0 = (uint)f2bf(f0.x) | ((uint)f2bf(f0.y) << 16);
        uint u1 = (uint)f2bf(f0.z) | ((uint)f2bf(f0.w) << 16);
        uint u2 = (uint)f2bf(f1.x) | ((uint)f2bf(f1.y) << 16);
        uint u3 = (uint)f2bf(f1.z) | ((uint)f2bf(f1.w) << 16);
        uint4 u = make_uint4(u0, u1, u2, u3);
        A[s] = *(short8*)&u;
    }
    for (int half = 0; half < 2; ++half) {
        for (int T12 = 0; T12 < 12; ++T12) {
            int T = half * 12 + T12;
            f32x4 acc = {0.f, 0.f, 0.f, 0.f};
            const ushort* bp = Wp + ((size_t)(T * 4) * 64 + lane) * 8;
            #pragma unroll
            for (int s = 0; s < 4; ++s) {
                uint4 u = *(const uint4*)(bp + s * 512);
                short8 B = *(short8*)&u;
                acc = __builtin_amdgcn_mfma_f32_16x16x32_bf16(A[s], B, acc, 0, 0, 0);
            }
            int c = T * 16 + m;               // original qkv column (for bias)
            int hq = T / 3, wvv = T % 3;      // head, {0=q,1=k,2=v}
            int hl = hq - half * 4;           // head local to this half (0..3)
            float bb = bqkv[c];
            #pragma unroll
            for (int r = 0; r < 4; ++r) {
                int nd16 = quad * 4 + r;
                float v = acc[r] + bb;
                if (wvv == 0)      lq[w][nd16][hl * 16 + m] = v;
                else if (wvv == 1) lk[w][nd16][hl * 16 + m] = f2bf(v);
                else               lv[w][nd16][hl * 16 + m] = f2bf(v);
            }
        }
        // flush this half: q cols [half*64,+64), k/v elems [half*64,+64) per
        // node; 16B/lane coalesced stores.
        #pragma unroll
        for (int rr = 0; rr < 4; ++rr) {
            int of = rr * 256 + lane * 4;          // float idx into lq[w]
            int ndq = of >> 6, colq = of & 63;
            float4 qv = *(const float4*)&lq[w][ndq][colq];
            int gq = node0 + ndq;
            if (gq < n)
                *(float4*)(qtab + (size_t)gq * N_DIM + half * 64 + colq) = qv;
        }
        #pragma unroll
        for (int rr = 0; rr < 2; ++rr) {
            int ou = rr * 512 + lane * 8;          // ushort idx (1024 total)
            int ndk = ou >> 6, elk = ou & 63;
            int gk = node0 + ndk;
            uint4 kv4 = *(const uint4*)&lk[w][ndk][elk];
            uint4 vv4 = *(const uint4*)&lv[w][ndk][elk];
            if (gk < n) {
                *(uint4*)(ktab + (size_t)gk * 128 + half * 64 + elk) = kv4;
                *(uint4*)(vtab + (size_t)gk * 128 + half * 64 + elk) = vv4;
            }
        }
    }
}

// ---------------------------------------------------------------------------
// Output GEMM via MFMA: (n x 128 bf16 agg) @ (128 x 128) + bout -> fp32 out.
// ---------------------------------------------------------------------------
__global__ __launch_bounds__(256) void out_gemm(const uint* __restrict__ aggb,
                                                const ushort* __restrict__ Wp,
                                                const float* __restrict__ bout,
                                                float* __restrict__ out, int n) {
    int w = threadIdx.x >> 6, lane = threadIdx.x & 63;
    int node0 = blockIdx.x * 64 + w * 16;
    int m = lane & 15, quad = lane >> 4;
    int arow = node0 + m; if (arow >= n) arow = n - 1;
    const uint* ar = aggb + (size_t)arow * 64;
    short8 A[4];
    #pragma unroll
    for (int s = 0; s < 4; ++s) {
        uint4 u = *(const uint4*)(ar + s * 16 + quad * 4);
        A[s] = *(short8*)&u;
    }
    for (int T = 0; T < 8; ++T) {
        f32x4 acc = {0.f, 0.f, 0.f, 0.f};
        const ushort* bp = Wp + ((size_t)(T * 4) * 64 + lane) * 8;
        #pragma unroll
        for (int s = 0; s < 4; ++s) {
            uint4 u = *(const uint4*)(bp + s * 512);
            short8 B = *(short8*)&u;
            acc = __builtin_amdgcn_mfma_f32_16x16x32_bf16(A[s], B, acc, 0, 0, 0);
        }
        int c = T * 16 + m;
        float bb = bout[c];
        #pragma unroll
        for (int r = 0; r < 4; ++r) {
            int nd = node0 + quad * 4 + r;
            if (nd < n) out[(size_t)nd * N_DIM + c] = acc[r] + bb;
        }
    }
}

// ---------------------------------------------------------------------------
// CSR build: exclusive scan of counts, sharded scatter of src ids.
// (histogram is fused into qkv_gemm; memset is fused into pack_w.)
// ---------------------------------------------------------------------------
__global__ void scan1_kernel(const int* __restrict__ counts, int* __restrict__ offs,
                             int* __restrict__ partials, int n) {
    __shared__ int ts[SCAN_B];
    int t = threadIdx.x;
    int base = blockIdx.x * SCAN_TILE + t * SCAN_V;
    int v[SCAN_V];
    int s = 0;
    #pragma unroll
    for (int i = 0; i < SCAN_V; ++i) { v[i] = (base + i < n) ? counts[base + i] : 0; s += v[i]; }
    ts[t] = s;
    __syncthreads();
    for (int off = 1; off < SCAN_B; off <<= 1) {
        int x = (t >= off) ? ts[t - off] : 0;
        __syncthreads();
        ts[t] += x;
        __syncthreads();
    }
    int run = (t > 0) ? ts[t - 1] : 0;
    if (t == SCAN_B - 1) partials[blockIdx.x] = ts[SCAN_B - 1];
    #pragma unroll
    for (int i = 0; i < SCAN_V; ++i) { if (base + i < n) offs[base + i] = run; run += v[i]; }
}

__global__ void scan2_kernel(int* __restrict__ partials, int P) {
    __shared__ int ps[1024];
    int t = threadIdx.x;
    ps[t] = (t < P) ? partials[t] : 0;
    __syncthreads();
    for (int off = 1; off < 1024; off <<= 1) {
        int x = (t >= off) ? ps[t - off] : 0;
        __syncthreads();
        ps[t] += x;
        __syncthreads();
    }
    if (t < P) partials[t] = (t > 0) ? ps[t - 1] : 0;
}

__global__ void scan3_kernel(int* __restrict__ offs, const int* __restrict__ partials,
                             int* __restrict__ cursor, int n, int nE) {
    int i = blockIdx.x * blockDim.x + threadIdx.x;
    if (i < n) {
        int o = offs[i] + partials[i / SCAN_TILE];
        offs[i] = o;
        cursor[i] = o;
    }
    if (i == 0) offs[n] = nE;
}

// Sharded scatter: 8 shards (r13 measured 4 shards as −4.3us regression —
// halving dst reads lost to breaking single-XCD affinity of each shard's
// cursor/esrc lines). block b owns dst range [shard*shardSize,...); shard =
// b&7 maps same-range blocks onto one XCD under round-robin dispatch.
// Correctness does not depend on the XCD mapping.
__global__ __launch_bounds__(256) void scatter_src_shard(const int* __restrict__ src,
                                                         const int* __restrict__ dst,
                                                         int* __restrict__ cursor,
                                                         int* __restrict__ esrc,
                                                         int nE, int shardSize) {
    int shard = blockIdx.x & 7;
    int sub   = blockIdx.x >> 3;
    int nsub  = gridDim.x >> 3;
    int lo = shard * shardSize;
    int hi = lo + shardSize;
    int stride = nsub * blockDim.x;
    for (int e = sub * blockDim.x + threadIdx.x; e < nE; e += stride) {
        int d = dst[e];
        if (d >= lo && d < hi) {
            int pos = atomicAdd(&cursor[d], 1);
            esrc[pos] = src[e];
        }
    }
}

// ---------------------------------------------------------------------------
// Fused attention v12 (FROZEN, 116.4us — at the gather floor: HBM 47.8%,
// VALU 65%, occ 83%): block-per-node, 128 threads, split 256B k/v rows,
// byte-offset so[], lockstep barriers, ALWAYS-padded batches, phase-A denom
// + end reduce, adaptive 32-edge chunks for deg>16.
// ---------------------------------------------------------------------------
__global__ void attn_kernel(const float* __restrict__ qtab,
                            const uint* __restrict__ kt, const uint* __restrict__ vt,
                            const int* __restrict__ esrc, const int* __restrict__ offs,
                            ushort* __restrict__ aggb, int n) {
    int node = blockIdx.x;
    int t = threadIdx.x;              // 0..127
    __shared__ float qs[16][8];       // q transposed: [d][h] (conflict-free)
    __shared__ uint  so[32];          // chunk src row BYTE offsets (0-padded)
    __shared__ float pp[32][8];       // chunk exp(score) (0-padded)
    __shared__ float lw[2][8];        // per-wave denom partials
    int h  = t >> 4, dd = t & 15;     // accumulate mapping
    int h2 = t & 7,  el = t >> 3;     // score mapping (0..15 across block)
    {
        float qv = qtab[(size_t)node * N_DIM + t];   // coalesced
        qs[dd][h] = qv;
    }
    int start = offs[node];
    int deg = offs[node + 1] - start;
    float lsum = 0.f, acc = 0.f;
    uint voffb = (uint)h * 32u + (uint)(dd >> 1) * 4u;   // v word byte off (256B row)
    uint sh = (dd & 1) ? 0u : 16u;    // branchless bf16 extract shift
    __syncthreads();

    for (int c0 = 0; c0 < deg; c0 += 32) {
        int rem = deg - c0;
        if (rem > 16) {
            // ---- 32-edge merged round ----
            int cn = rem < 32 ? rem : 32;
            if (t < 32) so[t] = (t < cn) ? ((uint)esrc[start + c0 + t] << 8) : 0u;
            __syncthreads();
            // phase A: edges el (el<16<=cn: unguarded) and el+16 (guarded;
            // padded slot loads row 0, L1-hot, pv forced to 0).
            const uint* kr0 = (const uint*)((const char*)kt + (so[el] + (uint)(h2 * 32)));
            const uint* kr1 = (const uint*)((const char*)kt + (so[el + 16] + (uint)(h2 * 32)));
            float d0 = kdot(kr0, qs, h2);
            float d1 = kdot(kr1, qs, h2);
            float pv0 = __expf(d0 * 0.25f);                             // 1/sqrt(16)
            float pv1 = (el + 16 < cn) ? __expf(d1 * 0.25f) : 0.f;
            pp[el][h2] = pv0;
            pp[el + 16][h2] = pv1;
            lsum += pv0 + pv1;
            __syncthreads();
            // phase B: 32 loads in flight (padded: row 0, p=0).
            float vacc = 0.f;
            uint vv[32];
            #pragma unroll
            for (int i = 0; i < 32; ++i)
                vv[i] = *(const uint*)((const char*)vt + (so[i] + voffb));
            #pragma unroll
            for (int i = 0; i < 32; ++i) {
                float p = pp[i][h];
                float v = __uint_as_float((vv[i] << sh) & 0xffff0000u);
                vacc = fmaf(p, v, vacc);
            }
            acc += vacc;
            __syncthreads();
        } else {
            // ---- 16-edge round ----
            int cn = rem;             // 1..16
            if (t < 16) so[t] = (t < cn) ? ((uint)esrc[start + c0 + t] << 8) : 0u;
            __syncthreads();
            float pv = 0.f;
            if (el < cn) {
                const uint* kr = (const uint*)((const char*)kt + (so[el] + (uint)(h2 * 32)));
                pv = __expf(kdot(kr, qs, h2) * 0.25f);
            }
            pp[el][h2] = pv;
            lsum += pv;
            __syncthreads();
            float vacc = 0.f;
            uint vv[16];
            #pragma unroll
            for (int i = 0; i < 16; ++i)
                vv[i] = *(const uint*)((const char*)vt + (so[i] + voffb));
            #pragma unroll
            for (int i = 0; i < 16; ++i) {
                float p = pp[i][h];
                float v = __uint_as_float((vv[i] << sh) & 0xffff0000u);
                vacc = fmaf(p, v, vacc);
            }
            acc += vacc;
            __syncthreads();
        }
    }
    // reduce lsum over el: el = bits 3..5 of the in-wave lane id (+ wave id).
    lsum += __shfl_xor(lsum, 8, 64);
    lsum += __shfl_xor(lsum, 16, 64);
    lsum += __shfl_xor(lsum, 32, 64);
    if ((t & 63) < 8) lw[t >> 6][t & 7] = lsum;   // per-wave partial per head
    __syncthreads();
    float L = lw[0][h] + lw[1][h];
    float rL = (L > 0.f) ? __frcp_rn(L) : 0.f;
    aggb[(size_t)node * N_DIM + t] = f2bf(acc * rL);
}

extern "C" void kernel_launch(void* const* d_in, const int* in_sizes, int n_in,
                              void* d_out, int out_size, void* d_ws, size_t ws_size,
                              hipStream_t stream) {
    const float* x    = (const float*)d_in[0];
    const float* Wqkv = (const float*)d_in[1];
    const float* bqkv = (const float*)d_in[2];
    const float* Wout = (const float*)d_in[3];
    const float* bout = (const float*)d_in[4];
    const int*   src  = (const int*)d_in[5];
    const int*   dst  = (const int*)d_in[6];
    float* out = (float*)d_out;

    const int n  = in_sizes[0] / N_DIM;   // 100000
    const int nE = in_sizes[5];           // 1600000

    // Workspace layout (4-byte units):
    uint* ws = (uint*)d_ws;
    float*  qtab   = (float*)ws;                          // n * 128 fp32
    uint*   ktab   = ws + (size_t)n * 128;                // n * 64 uint (128 bf16)
    uint*   vtab   = ktab + (size_t)n * 64;               // n * 64 uint (128 bf16)
    uint*   aggb   = vtab + (size_t)n * 64;               // n * 64 uint (128 bf16)
    ushort* WpQ    = (ushort*)(aggb + (size_t)n * 64);    // 128*384 bf16
    ushort* WpO    = WpQ + 128 * QKV_DIM;                 // 128*128 bf16
    int*    counts = (int*)(WpO + 128 * N_DIM);           // n
    int*    offs   = counts + n;                          // n + 1
    int*    cursor = offs + n + 1;                        // n
    int*    partials = cursor + n;                        // up to 1024
    int*    esrc   = partials + 1024;                     // nE

    int packWork = 128 * (QKV_DIM + N_DIM);
    int pwGrid = ((n > packWork ? n : packWork) + 255) / 256;
    pack_w_kernel<<<pwGrid, 256, 0, stream>>>(Wqkv, Wout, WpQ, WpO, counts, n);

    qkv_gemm<<<(n + 63) / 64, 256, 0, stream>>>(x, WpQ, bqkv, qtab,
                                                (ushort*)ktab, (ushort*)vtab,
                                                dst, counts, n, nE);

    int P = (n + SCAN_TILE - 1) / SCAN_TILE;              // 98
    scan1_kernel<<<P, SCAN_B, 0, stream>>>(counts, offs, partials, n);
    scan2_kernel<<<1, 1024, 0, stream>>>(partials, P);
    scan3_kernel<<<(n + 255) / 256, 256, 0, stream>>>(offs, partials, cursor, n, nE);

    int shardSize = (n + 7) / 8;                          // 12500
    scatter_src_shard<<<8 * 128, 256, 0, stream>>>(src, dst, cursor, esrc, nE, shardSize);

    attn_kernel<<<n, 128, 0, stream>>>(qtab, ktab, vtab, esrc, offs, (ushort*)aggb, n);

    out_gemm<<<(n + 63) / 64, 256, 0, stream>>>(aggb, WpO, bout, out, n);
}